// Round 1
// baseline (441.743 us; speedup 1.0000x reference)
//
#include <hip/hip_runtime.h>

// CIN fused 3-layer kernel, fp32 VALU version.
// B=1024, F=39, D=16, L=128 per layer. Slices = B*D = 16384.
// Block: 1024 threads = 16 waves; lane (0..63) = slice within block's group of 64;
// wave w handles output channels [8w, 8w+8). Grid: 256 blocks (1 per CU).
// W loads are wave-uniform (scalar-broadcast); x/h live in registers per lane.

#define NF  39
#define DD  16
#define LCH 128
#define HSTRIDE 68   // 64 + 4 pad: keeps float4 16B alignment, conflicts negligible (2 uses/layer)

__device__ __forceinline__ void reduce_store(float (&acc)[8], float* outp, bool red_lane) {
    // sum over d = lane&15 (16 lanes share one b), store from lanes 0,16,32,48
    #pragma unroll
    for (int i = 0; i < 8; ++i) {
        float v = acc[i];
        v += __shfl_xor(v, 1, 64);
        v += __shfl_xor(v, 2, 64);
        v += __shfl_xor(v, 4, 64);
        v += __shfl_xor(v, 8, 64);
        if (red_lane) outp[i] = v;
    }
}

__device__ __forceinline__ void layer64(const float* __restrict__ W,
                                        const float* __restrict__ bias,
                                        const float* xrow,
                                        const float (&h)[64],
                                        float (&acc)[8],
                                        int cbase)
{
    #pragma unroll
    for (int i = 0; i < 8; ++i) acc[i] = bias[cbase + i];
    for (int f = 0; f < NF; ++f) {
        float xf = xrow[f];                      // per-lane LDS read, once per f
        const float* wp = W + (f * 64) * LCH + cbase;  // wave-uniform
        #pragma unroll
        for (int g = 0; g < 64; ++g) {
            float p = xf * h[g];
            const float4* w4 = (const float4*)(wp + g * LCH);
            float4 wa = w4[0];
            float4 wb = w4[1];
            acc[0] = fmaf(wa.x, p, acc[0]);
            acc[1] = fmaf(wa.y, p, acc[1]);
            acc[2] = fmaf(wa.z, p, acc[2]);
            acc[3] = fmaf(wa.w, p, acc[3]);
            acc[4] = fmaf(wb.x, p, acc[4]);
            acc[5] = fmaf(wb.y, p, acc[5]);
            acc[6] = fmaf(wb.z, p, acc[6]);
            acc[7] = fmaf(wb.w, p, acc[7]);
        }
    }
    #pragma unroll
    for (int i = 0; i < 8; ++i) acc[i] = fmaxf(acc[i], 0.0f);
}

__global__ __launch_bounds__(1024) void cin_fused(
    const float* __restrict__ x,
    const float* __restrict__ W0,
    const float* __restrict__ W1,
    const float* __restrict__ W2,
    const float* __restrict__ b0,
    const float* __restrict__ b1,
    const float* __restrict__ b2,
    float* __restrict__ out)
{
    __shared__ float x_lds[64 * NF];
    __shared__ float h_lds[64 * HSTRIDE];

    const int tid   = threadIdx.x;
    const int lane  = tid & 63;
    const int wu    = __builtin_amdgcn_readfirstlane(tid >> 6);  // wave id, provably uniform
    const int cbase = wu * 8;

    const int slice0 = blockIdx.x * 64;

    // stage this block's 64 slices of x into LDS: x_lds[sl][f]
    for (int idx = tid; idx < 64 * NF; idx += 1024) {
        int sl = idx / NF;
        int f  = idx - sl * NF;
        int s  = slice0 + sl;
        x_lds[idx] = x[((s >> 4) * NF + f) * DD + (s & 15)];
    }
    __syncthreads();

    const int  b        = (slice0 + lane) >> 4;
    float*     outb     = out + b * 256;
    const bool red_lane = ((lane & 15) == 0);
    const float* xrow   = &x_lds[lane * NF];

    float acc[8];

    // ---------------- layer 0: h = x (Fk = 39) ----------------
    float xr[NF];
    #pragma unroll
    for (int g = 0; g < NF; ++g) xr[g] = xrow[g];

    #pragma unroll
    for (int i = 0; i < 8; ++i) acc[i] = b0[cbase + i];

    for (int f = 0; f < NF; ++f) {
        float xf = xrow[f];
        const float* wp = W0 + (f * NF) * LCH + cbase;
        #pragma unroll
        for (int g = 0; g < NF; ++g) {
            float p = xf * xr[g];
            const float4* w4 = (const float4*)(wp + g * LCH);
            float4 wa = w4[0];
            float4 wb = w4[1];
            acc[0] = fmaf(wa.x, p, acc[0]);
            acc[1] = fmaf(wa.y, p, acc[1]);
            acc[2] = fmaf(wa.z, p, acc[2]);
            acc[3] = fmaf(wa.w, p, acc[3]);
            acc[4] = fmaf(wb.x, p, acc[4]);
            acc[5] = fmaf(wb.y, p, acc[5]);
            acc[6] = fmaf(wb.z, p, acc[6]);
            acc[7] = fmaf(wb.w, p, acc[7]);
        }
    }
    #pragma unroll
    for (int i = 0; i < 8; ++i) acc[i] = fmaxf(acc[i], 0.0f);

    if (wu >= 8) {
        // direct = cur[:, 64:128] -> out channels 0..63
        reduce_store(acc, outb + (cbase - 64), red_lane);
    } else {
        // h = cur[:, 0:64]
        #pragma unroll
        for (int i = 0; i < 8; ++i) h_lds[lane * HSTRIDE + cbase + i] = acc[i];
    }
    __syncthreads();

    float h[64];
    #pragma unroll
    for (int j = 0; j < 16; ++j) {
        float4 t = *(const float4*)(&h_lds[lane * HSTRIDE + 4 * j]);
        h[4*j+0] = t.x; h[4*j+1] = t.y; h[4*j+2] = t.z; h[4*j+3] = t.w;
    }
    __syncthreads();   // everyone has h in regs before h_lds is overwritten

    // ---------------- layer 1 (Fk = 64) ----------------
    layer64(W1, b1, xrow, h, acc, cbase);

    if (wu >= 8) {
        // direct = cur[:, 64:128] -> out channels 64..127  (oc = cbase)
        reduce_store(acc, outb + cbase, red_lane);
    } else {
        #pragma unroll
        for (int i = 0; i < 8; ++i) h_lds[lane * HSTRIDE + cbase + i] = acc[i];
    }
    __syncthreads();

    #pragma unroll
    for (int j = 0; j < 16; ++j) {
        float4 t = *(const float4*)(&h_lds[lane * HSTRIDE + 4 * j]);
        h[4*j+0] = t.x; h[4*j+1] = t.y; h[4*j+2] = t.z; h[4*j+3] = t.w;
    }
    __syncthreads();

    // ---------------- layer 2 (Fk = 64), all channels direct ----------------
    layer64(W2, b2, xrow, h, acc, cbase);

    // direct = cur[:, 0:128] -> out channels 128..255
    reduce_store(acc, outb + 128 + cbase, red_lane);
}

extern "C" void kernel_launch(void* const* d_in, const int* in_sizes, int n_in,
                              void* d_out, int out_size, void* d_ws, size_t ws_size,
                              hipStream_t stream) {
    const float* x  = (const float*)d_in[0];
    const float* W0 = (const float*)d_in[1];
    const float* W1 = (const float*)d_in[2];
    const float* W2 = (const float*)d_in[3];
    const float* b0 = (const float*)d_in[4];
    const float* b1 = (const float*)d_in[5];
    const float* b2 = (const float*)d_in[6];
    float* out = (float*)d_out;

    cin_fused<<<256, 1024, 0, stream>>>(x, W0, W1, W2, b0, b1, b2, out);
}

// Round 2
// 199.818 us; speedup vs baseline: 2.2107x; 2.2107x over previous
//
#include <hip/hip_runtime.h>

// CIN fused 3-layer, bf16 MFMA version.
// Unified view: all layers are M=16384(slices) x N=128 x K=2496 GEMMs where
// A[sl, f*64+g] = x[sl,f]*h[sl,g] (layer0: h=x zero-padded g>=39), h_{l+1} =
// relu(cur)[:, 0:64], direct halves reduced over d into out.
//
// prep kernel: W -> bf16 tiles in d_ws, frag-ready layout per 32-K tile:
//   wt[(l*78+kt)*4096 + n*32 + q*8 + j] = bf16(W_l[k=kt*32+q*8+j][n])
// main kernel: 256 blocks x 512 thr (8 waves); M=64/block (4 b's), N=128.
// Wave = 2 m-tiles x 2 n-tiles of mfma_f32_16x16x32_bf16; A-frags built in
// registers from LDS bf16 h; B tiles staged via global_load_lds (16B),
// double-buffered.

#define NF     39
#define KPAD   2496
#define NKT    78
#define LCH    128
#define NLAYER 3

typedef __bf16        bf16x8 __attribute__((ext_vector_type(8)));
typedef unsigned int  uint4v __attribute__((ext_vector_type(4)));
typedef float         f32x4  __attribute__((ext_vector_type(4)));

__device__ __forceinline__ unsigned short f2bf_rne(float f) {
    unsigned u = __float_as_uint(f);
    u += 0x7fffu + ((u >> 16) & 1u);
    return (unsigned short)(u >> 16);
}

// ---------------- prep: W fp32 -> bf16 frag-ready tiles in ws ----------------
__global__ void cin_prep(const float* __restrict__ W0,
                         const float* __restrict__ W1,
                         const float* __restrict__ W2,
                         unsigned short* __restrict__ wt)
{
    int t = blockIdx.x * blockDim.x + threadIdx.x;   // = ((l*78+kt)*128 + n)*4 + q
    if (t >= NLAYER * NKT * LCH * 4) return;
    const int q   = t & 3;
    const int n   = (t >> 2) & 127;
    const int ktl = t >> 9;                // l*78 + kt
    const int l   = ktl / NKT;
    const int kt  = ktl - l * NKT;
    const float* W = (l == 0) ? W0 : (l == 1) ? W1 : W2;

    unsigned short v[8];
    #pragma unroll
    for (int j = 0; j < 8; ++j) {
        const int k = kt * 32 + q * 8 + j;
        const int f = k >> 6, g = k & 63;
        float w = 0.0f;
        if (l == 0) { if (g < NF) w = W[(f * NF + g) * LCH + n]; }
        else        { w = W[k * LCH + n]; }
        v[j] = f2bf_rne(w);
    }
    uint4v pv;
    #pragma unroll
    for (int i = 0; i < 4; ++i)
        pv[i] = (unsigned)v[2 * i] | ((unsigned)v[2 * i + 1] << 16);
    ((uint4v*)wt)[t] = pv;   // 16B coalesced store
}

// ---------------- main ----------------
__global__ __launch_bounds__(512) void cin_mfma(
    const float* __restrict__ x,
    const unsigned short* __restrict__ wt,
    const float* __restrict__ b0p,
    const float* __restrict__ b1p,
    const float* __restrict__ b2p,
    float* __restrict__ out)
{
    // hfrag[gblk][sl][j] : h[sl][g = gblk*8+j] as bf16  (8 KB)
    __shared__ __align__(16) unsigned short hfrag[8 * 64 * 8];
    __shared__ unsigned short xl[NF * 64];                 // [f][sl] bf16
    __shared__ __align__(16) unsigned short wbuf[2][4096]; // [n*32 + q*8 + j]
    __shared__ float biasl[NLAYER * LCH];

    const int tid  = threadIdx.x;
    const int lane = tid & 63;
    const int w    = tid >> 6;      // wave 0..7
    const int q    = lane >> 4;     // quad 0..3
    const int c    = lane & 15;
    const int mg   = w >> 2;        // 0..1 -> m-tiles {2mg, 2mg+1}
    const int ng   = w & 3;         // 0..3 -> n-tiles {2ng, 2ng+1}
    const int b0   = blockIdx.x * 4;

    const int mt0 = mg * 2, mt1 = mg * 2 + 1;
    const int nt0 = ng * 2, nt1 = ng * 2 + 1;

    // zero hfrag (covers layer-0 padding g in [39,64))
    {
        f32x4 z = {0.f, 0.f, 0.f, 0.f};
        ((f32x4*)hfrag)[tid] = z;   // 512 * 16B = 8 KB exactly
    }
    for (int t = tid; t < NLAYER * LCH; t += 512) {
        biasl[t] = (t < 128) ? b0p[t] : (t < 256) ? b1p[t - 128] : b2p[t - 256];
    }
    __syncthreads();   // zeros visible before selective overwrite below

    // stage x: xl[f][sl] and hfrag (layer-0 h = x)
    for (int t = tid; t < 4 * NF * 16; t += 512) {
        const int lb = t / (NF * 16);
        const int r  = t - lb * (NF * 16);
        const int f  = r >> 4;
        const int d  = r & 15;
        const float v = x[(((b0 + lb) * NF) + f) * 16 + d];
        const unsigned short bv = f2bf_rne(v);
        const int sl = lb * 16 + d;
        xl[f * 64 + sl] = bv;
        hfrag[((f >> 3) * 64 + sl) * 8 + (f & 7)] = bv;
    }

    // prefetch W tile (layer 0, kt 0) into wbuf[0]
    {
        const unsigned short* gsrc = wt + w * 512 + lane * 8;
        __builtin_amdgcn_global_load_lds(
            (const __attribute__((address_space(1))) void*)gsrc,
            (__attribute__((address_space(3))) void*)(&wbuf[0][w * 512]),
            16, 0, 0);
    }
    __syncthreads();   // x, hfrag, bias, first W tile all ready

    int cur = 0;
    #pragma unroll 1
    for (int l = 0; l < NLAYER; ++l) {
        f32x4 acc00 = {0,0,0,0}, acc01 = {0,0,0,0};
        f32x4 acc10 = {0,0,0,0}, acc11 = {0,0,0,0};

        #pragma unroll 1
        for (int kt = 0; kt < NKT; ++kt) {
            // prefetch next tile into the other buffer
            int nl = l, nkt = kt + 1;
            if (nkt == NKT) { nl = l + 1; nkt = 0; }
            if (nl < NLAYER) {
                const unsigned short* gsrc =
                    wt + (nl * NKT + nkt) * 4096 + w * 512 + lane * 8;
                __builtin_amdgcn_global_load_lds(
                    (const __attribute__((address_space(1))) void*)gsrc,
                    (__attribute__((address_space(3))) void*)(&wbuf[cur ^ 1][w * 512]),
                    16, 0, 0);
            }

            const int f    = kt >> 1;                // uniform over the 32-K window
            const int gblk = (kt * 4 + q) & 7;       // g = gblk*8 + j

            // x scalars (bf16 -> f32 by shift)
            const float xf0 = __uint_as_float((unsigned)xl[f * 64 + mt0 * 16 + c] << 16);
            const float xf1 = __uint_as_float((unsigned)xl[f * 64 + mt1 * 16 + c] << 16);

            // h fragments (conflict-free b128)
            const uint4v hu0 = *((const uint4v*)&hfrag[(gblk * 64 + mt0 * 16 + c) * 8]);
            const uint4v hu1 = *((const uint4v*)&hfrag[(gblk * 64 + mt1 * 16 + c) * 8]);

            // B fragments (contiguous 1 KB per wave)
            const bf16x8 bv0 = *((const bf16x8*)&wbuf[cur][(nt0 * 16 + c) * 32 + q * 8]);
            const bf16x8 bv1 = *((const bf16x8*)&wbuf[cur][(nt1 * 16 + c) * 32 + q * 8]);

            // build A frags: a = bf16_trunc(xf * h)
            uint4v au0, au1;
            #pragma unroll
            for (int i = 0; i < 4; ++i) {
                unsigned d0 = hu0[i];
                float lo = __uint_as_float(d0 << 16) * xf0;
                float hi = __uint_as_float(d0 & 0xffff0000u) * xf0;
                au0[i] = (__float_as_uint(hi) & 0xffff0000u) | (__float_as_uint(lo) >> 16);
                unsigned d1 = hu1[i];
                float lo1 = __uint_as_float(d1 << 16) * xf1;
                float hi1 = __uint_as_float(d1 & 0xffff0000u) * xf1;
                au1[i] = (__float_as_uint(hi1) & 0xffff0000u) | (__float_as_uint(lo1) >> 16);
            }
            const bf16x8 av0 = __builtin_bit_cast(bf16x8, au0);
            const bf16x8 av1 = __builtin_bit_cast(bf16x8, au1);

            acc00 = __builtin_amdgcn_mfma_f32_16x16x32_bf16(av0, bv0, acc00, 0, 0, 0);
            acc01 = __builtin_amdgcn_mfma_f32_16x16x32_bf16(av0, bv1, acc01, 0, 0, 0);
            acc10 = __builtin_amdgcn_mfma_f32_16x16x32_bf16(av1, bv0, acc10, 0, 0, 0);
            acc11 = __builtin_amdgcn_mfma_f32_16x16x32_bf16(av1, bv1, acc11, 0, 0, 0);

            __syncthreads();   // drains DMA (next tile ready), orders buffer reuse
            cur ^= 1;
        }

        // ---------------- epilogue for layer l ----------------
        const int ch0 = nt0 * 16 + c, ch1 = nt1 * 16 + c;
        const float bias0 = biasl[l * LCH + ch0];
        const float bias1 = biasl[l * LCH + ch1];
        f32x4 v00, v01, v10, v11;
        #pragma unroll
        for (int r = 0; r < 4; ++r) {
            v00[r] = fmaxf(acc00[r] + bias0, 0.f);
            v01[r] = fmaxf(acc01[r] + bias1, 0.f);
            v10[r] = fmaxf(acc10[r] + bias0, 0.f);
            v11[r] = fmaxf(acc11[r] + bias1, 0.f);
        }

        if (l < 2 && ng < 2) {
            // h channels (ch < 64): write next layer's h into hfrag
            #pragma unroll
            for (int r = 0; r < 4; ++r) {
                const int sl0 = mt0 * 16 + q * 4 + r;   // C/D row = q*4+r  [m89]
                const int sl1 = mt1 * 16 + q * 4 + r;
                hfrag[((ch0 >> 3) * 64 + sl0) * 8 + (ch0 & 7)] = f2bf_rne(v00[r]);
                hfrag[((ch1 >> 3) * 64 + sl0) * 8 + (ch1 & 7)] = f2bf_rne(v01[r]);
                hfrag[((ch0 >> 3) * 64 + sl1) * 8 + (ch0 & 7)] = f2bf_rne(v10[r]);
                hfrag[((ch1 >> 3) * 64 + sl1) * 8 + (ch1 & 7)] = f2bf_rne(v11[r]);
            }
        } else {
            // direct channels: reduce over d (rows) and store
            // l==0: ch 64..127 -> out 0..63 ; l==1: ch 64..127 -> out 64..127 ;
            // l==2: ch 0..127 -> out 128..255
            const int oco = (l == 0) ? -64 : (l == 1) ? 0 : 128;
            float s0 = v00[0] + v00[1] + v00[2] + v00[3];
            float s1 = v01[0] + v01[1] + v01[2] + v01[3];
            float s2 = v10[0] + v10[1] + v10[2] + v10[3];
            float s3 = v11[0] + v11[1] + v11[2] + v11[3];
            s0 += __shfl_xor(s0, 16, 64); s0 += __shfl_xor(s0, 32, 64);
            s1 += __shfl_xor(s1, 16, 64); s1 += __shfl_xor(s1, 32, 64);
            s2 += __shfl_xor(s2, 16, 64); s2 += __shfl_xor(s2, 32, 64);
            s3 += __shfl_xor(s3, 16, 64); s3 += __shfl_xor(s3, 32, 64);
            if (lane < 16) {
                out[(b0 + mt0) * 256 + ch0 + oco] = s0;
                out[(b0 + mt0) * 256 + ch1 + oco] = s1;
                out[(b0 + mt1) * 256 + ch0 + oco] = s2;
                out[(b0 + mt1) * 256 + ch1 + oco] = s3;
            }
        }
        __syncthreads();   // h writes visible before next layer's A-builds
    }
}

extern "C" void kernel_launch(void* const* d_in, const int* in_sizes, int n_in,
                              void* d_out, int out_size, void* d_ws, size_t ws_size,
                              hipStream_t stream) {
    const float* x  = (const float*)d_in[0];
    const float* W0 = (const float*)d_in[1];
    const float* W1 = (const float*)d_in[2];
    const float* W2 = (const float*)d_in[3];
    const float* b0 = (const float*)d_in[4];
    const float* b1 = (const float*)d_in[5];
    const float* b2 = (const float*)d_in[6];
    float* out = (float*)d_out;
    unsigned short* wt = (unsigned short*)d_ws;  // needs 3*78*4096*2 B = 1.87 MB

    const int prep_elems = NLAYER * NKT * LCH * 4;       // 119808 16B-stores
    cin_prep<<<(prep_elems + 255) / 256, 256, 0, stream>>>(W0, W1, W2, wt);
    cin_mfma<<<256, 512, 0, stream>>>(x, wt, b0, b1, b2, out);
}

// Round 3
// 129.769 us; speedup vs baseline: 3.4041x; 1.5398x over previous
//
#include <hip/hip_runtime.h>

// CIN fused 3-layer, bf16 MFMA, S_f-decomposition version.
// cur[sl,n] = sum_f x_f[sl] * S_f[sl,n],  S_f = sum_g h_g[sl] * W[f*64+g, n].
// h is the MFMA A-operand directly (K=64 per f => 2 ksteps of 16x16x32);
// A-frags hoisted into registers once per layer. x applied in fp32 VALU.
//
// wt layout (prep output), tile tl = l*39+f (layer0 g zero-padded to 64):
//   wt[tl*8192 + ((ks*4 + q)*128 + n)*8 + j] = bf16(W_l[f*64 + ks*32+q*8+j][n])
// => B-frag read for (ks, ntile): contiguous 256 B per quad (conflict-free),
// => prep reads coalesced over n, writes coalesced dwordx4.

#define NF     39
#define LCH    128
#define NLAYER 3
#define NFT    (NLAYER * NF)   // 117 f-tiles

typedef __bf16        bf16x8 __attribute__((ext_vector_type(8)));
typedef unsigned int  uint4v __attribute__((ext_vector_type(4)));
typedef float         f32x4  __attribute__((ext_vector_type(4)));

__device__ __forceinline__ unsigned short f2bf_rne(float f) {
    unsigned u = __float_as_uint(f);
    u += 0x7fffu + ((u >> 16) & 1u);
    return (unsigned short)(u >> 16);
}

// ---------------- prep: W fp32 -> bf16 frag-ready tiles in ws ----------------
__global__ void cin_prep(const float* __restrict__ W0,
                         const float* __restrict__ W1,
                         const float* __restrict__ W2,
                         unsigned short* __restrict__ wt)
{
    const int t = blockIdx.x * blockDim.x + threadIdx.x; // ((tl*2+ks)*4+q)*128 + n
    if (t >= NFT * 1024) return;
    const int n  = t & 127;
    const int q  = (t >> 7) & 3;
    const int ks = (t >> 9) & 1;
    const int tl = t >> 10;
    const int l  = tl / NF;
    const int f  = tl - l * NF;
    const float* W = (l == 0) ? W0 : (l == 1) ? W1 : W2;

    unsigned short v[8];
    #pragma unroll
    for (int j = 0; j < 8; ++j) {
        const int g = ks * 32 + q * 8 + j;
        float w = 0.0f;
        if (l == 0) { if (g < NF) w = W[(f * NF + g) * LCH + n]; }
        else        { w = W[(f * 64 + g) * LCH + n]; }
        v[j] = f2bf_rne(w);
    }
    uint4v pv;
    #pragma unroll
    for (int i = 0; i < 4; ++i)
        pv[i] = (unsigned)v[2 * i] | ((unsigned)v[2 * i + 1] << 16);
    ((uint4v*)wt)[t] = pv;   // 16B coalesced
}

// ---------------- main ----------------
__global__ __launch_bounds__(512) void cin_mfma(
    const float* __restrict__ x,
    const unsigned short* __restrict__ wt,
    const float* __restrict__ b0p,
    const float* __restrict__ b1p,
    const float* __restrict__ b2p,
    float* __restrict__ out)
{
    __shared__ __align__(16) unsigned short hfrag[8 * 64 * 8];  // [gblk][sl][j], 8 KB
    __shared__ float xf32[NF * 64];                             // [f][sl] fp32
    __shared__ __align__(16) unsigned short wbuf[2][8192];      // [ks][q][n][j], 16 KB each
    __shared__ float biasl[NLAYER * LCH];

    const int tid  = threadIdx.x;
    const int lane = tid & 63;
    const int w    = tid >> 6;
    const int q    = lane >> 4;
    const int c    = lane & 15;
    const int mg   = w >> 2;
    const int ng   = w & 3;
    const int bb   = blockIdx.x * 4;

    const int mt0 = mg * 2, mt1 = mg * 2 + 1;
    const int nt0 = ng * 2, nt1 = ng * 2 + 1;

    // zero hfrag (covers layer-0 padding g in [39,64))
    {
        f32x4 z = {0.f, 0.f, 0.f, 0.f};
        ((f32x4*)hfrag)[tid] = z;   // 512*16B = 8 KB exactly
    }
    for (int t = tid; t < NLAYER * LCH; t += 512)
        biasl[t] = (t < 128) ? b0p[t] : (t < 256) ? b1p[t - 128] : b2p[t - 256];
    __syncthreads();

    // stage x (contiguous 2496 floats for this block's 4 b's)
    for (int i = tid; i < 4 * NF * 16; i += 512) {
        const float v = x[bb * (NF * 16) + i];
        const int lb = i / (NF * 16);
        const int r  = i - lb * (NF * 16);
        const int f  = r >> 4;
        const int d  = r & 15;
        const int sl = lb * 16 + d;
        xf32[f * 64 + sl] = v;
        hfrag[((f >> 3) * 64 + sl) * 8 + (f & 7)] = f2bf_rne(v);
    }

    // initial DMA: tile 0 -> wbuf[0]
    {
        const unsigned short* src = wt + tid * 8;
        #pragma unroll
        for (int i = 0; i < 2; ++i)
            __builtin_amdgcn_global_load_lds(
                (const __attribute__((address_space(1))) void*)(src + i * 4096),
                (__attribute__((address_space(3))) void*)(&wbuf[0][tid * 8 + i * 4096]),
                16, 0, 0);
    }
    __syncthreads();

    int cur = 0;
    #pragma unroll 1
    for (int l = 0; l < NLAYER; ++l) {
        // hoist A-frags (h) for this layer: a[ks][mt]
        const bf16x8 a00 = *((const bf16x8*)&hfrag[((0 * 4 + q) * 64 + mt0 * 16 + c) * 8]);
        const bf16x8 a01 = *((const bf16x8*)&hfrag[((0 * 4 + q) * 64 + mt1 * 16 + c) * 8]);
        const bf16x8 a10 = *((const bf16x8*)&hfrag[((1 * 4 + q) * 64 + mt0 * 16 + c) * 8]);
        const bf16x8 a11 = *((const bf16x8*)&hfrag[((1 * 4 + q) * 64 + mt1 * 16 + c) * 8]);

        f32x4 cur00 = {0,0,0,0}, cur01 = {0,0,0,0};
        f32x4 cur10 = {0,0,0,0}, cur11 = {0,0,0,0};
        const f32x4 z = {0,0,0,0};

        #pragma unroll 1
        for (int f = 0; f < NF; ++f) {
            const int tl = l * NF + f;
            if (tl + 1 < NFT) {
                const unsigned short* src = wt + (size_t)(tl + 1) * 8192 + tid * 8;
                unsigned short* dst = &wbuf[cur ^ 1][tid * 8];
                #pragma unroll
                for (int i = 0; i < 2; ++i)
                    __builtin_amdgcn_global_load_lds(
                        (const __attribute__((address_space(1))) void*)(src + i * 4096),
                        (__attribute__((address_space(3))) void*)(dst + i * 4096),
                        16, 0, 0);
            }

            // B-frags: contiguous 256 B per quad (conflict-free)
            const bf16x8 b00 = *((const bf16x8*)&wbuf[cur][((0 * 4 + q) * 128 + nt0 * 16 + c) * 8]);
            const bf16x8 b01 = *((const bf16x8*)&wbuf[cur][((0 * 4 + q) * 128 + nt1 * 16 + c) * 8]);
            const bf16x8 b10 = *((const bf16x8*)&wbuf[cur][((1 * 4 + q) * 128 + nt0 * 16 + c) * 8]);
            const bf16x8 b11 = *((const bf16x8*)&wbuf[cur][((1 * 4 + q) * 128 + nt1 * 16 + c) * 8]);

            // x rows (fp32, LDS broadcast: all 16 c-lanes same address)
            const f32x4 xr0 = *((const f32x4*)&xf32[f * 64 + mt0 * 16 + q * 4]);
            const f32x4 xr1 = *((const f32x4*)&xf32[f * 64 + mt1 * 16 + q * 4]);

            // S_f per tile: 2-MFMA chain from zero acc, then cur += x_f * S
            f32x4 s00 = __builtin_amdgcn_mfma_f32_16x16x32_bf16(a00, b00, z,   0, 0, 0);
            s00       = __builtin_amdgcn_mfma_f32_16x16x32_bf16(a10, b10, s00, 0, 0, 0);
            f32x4 s01 = __builtin_amdgcn_mfma_f32_16x16x32_bf16(a00, b01, z,   0, 0, 0);
            s01       = __builtin_amdgcn_mfma_f32_16x16x32_bf16(a10, b11, s01, 0, 0, 0);
            f32x4 s10 = __builtin_amdgcn_mfma_f32_16x16x32_bf16(a01, b00, z,   0, 0, 0);
            s10       = __builtin_amdgcn_mfma_f32_16x16x32_bf16(a11, b10, s10, 0, 0, 0);
            f32x4 s11 = __builtin_amdgcn_mfma_f32_16x16x32_bf16(a01, b01, z,   0, 0, 0);
            s11       = __builtin_amdgcn_mfma_f32_16x16x32_bf16(a11, b11, s11, 0, 0, 0);

            #pragma unroll
            for (int r = 0; r < 4; ++r) {
                cur00[r] = fmaf(xr0[r], s00[r], cur00[r]);
                cur01[r] = fmaf(xr0[r], s01[r], cur01[r]);
                cur10[r] = fmaf(xr1[r], s10[r], cur10[r]);
                cur11[r] = fmaf(xr1[r], s11[r], cur11[r]);
            }

            __syncthreads();   // next W tile resident; orders wbuf reuse
            cur ^= 1;
        }

        // ---------------- epilogue for layer l ----------------
        const int ch0 = nt0 * 16 + c, ch1 = nt1 * 16 + c;
        const float bias0 = biasl[l * LCH + ch0];
        const float bias1 = biasl[l * LCH + ch1];
        f32x4 v00, v01, v10, v11;
        #pragma unroll
        for (int r = 0; r < 4; ++r) {
            v00[r] = fmaxf(cur00[r] + bias0, 0.f);
            v01[r] = fmaxf(cur01[r] + bias1, 0.f);
            v10[r] = fmaxf(cur10[r] + bias0, 0.f);
            v11[r] = fmaxf(cur11[r] + bias1, 0.f);
        }

        if (l < 2 && ng < 2) {
            // h channels (ch < 64): write next layer's h (C row = q*4+r)
            #pragma unroll
            for (int r = 0; r < 4; ++r) {
                const int sl0 = mt0 * 16 + q * 4 + r;
                const int sl1 = mt1 * 16 + q * 4 + r;
                hfrag[((ch0 >> 3) * 64 + sl0) * 8 + (ch0 & 7)] = f2bf_rne(v00[r]);
                hfrag[((ch1 >> 3) * 64 + sl0) * 8 + (ch1 & 7)] = f2bf_rne(v01[r]);
                hfrag[((ch0 >> 3) * 64 + sl1) * 8 + (ch0 & 7)] = f2bf_rne(v10[r]);
                hfrag[((ch1 >> 3) * 64 + sl1) * 8 + (ch1 & 7)] = f2bf_rne(v11[r]);
            }
        } else {
            // direct channels: reduce over d (C rows) and store
            const int oco = (l == 0) ? -64 : (l == 1) ? 0 : 128;
            float s0 = v00[0] + v00[1] + v00[2] + v00[3];
            float s1 = v01[0] + v01[1] + v01[2] + v01[3];
            float s2 = v10[0] + v10[1] + v10[2] + v10[3];
            float s3 = v11[0] + v11[1] + v11[2] + v11[3];
            s0 += __shfl_xor(s0, 16, 64); s0 += __shfl_xor(s0, 32, 64);
            s1 += __shfl_xor(s1, 16, 64); s1 += __shfl_xor(s1, 32, 64);
            s2 += __shfl_xor(s2, 16, 64); s2 += __shfl_xor(s2, 32, 64);
            s3 += __shfl_xor(s3, 16, 64); s3 += __shfl_xor(s3, 32, 64);
            if (lane < 16) {
                out[(bb + mt0) * 256 + ch0 + oco] = s0;
                out[(bb + mt0) * 256 + ch1 + oco] = s1;
                out[(bb + mt1) * 256 + ch0 + oco] = s2;
                out[(bb + mt1) * 256 + ch1 + oco] = s3;
            }
        }
        __syncthreads();   // h writes visible before next layer's A-hoist
    }
}

extern "C" void kernel_launch(void* const* d_in, const int* in_sizes, int n_in,
                              void* d_out, int out_size, void* d_ws, size_t ws_size,
                              hipStream_t stream) {
    const float* x  = (const float*)d_in[0];
    const float* W0 = (const float*)d_in[1];
    const float* W1 = (const float*)d_in[2];
    const float* W2 = (const float*)d_in[3];
    const float* b0 = (const float*)d_in[4];
    const float* b1 = (const float*)d_in[5];
    const float* b2 = (const float*)d_in[6];
    float* out = (float*)d_out;
    unsigned short* wt = (unsigned short*)d_ws;  // 117*8192*2 B = 1.87 MB

    const int prep_threads = NFT * 1024;         // 119808
    cin_prep<<<(prep_threads + 255) / 256, 256, 0, stream>>>(W0, W1, W2, wt);
    cin_mfma<<<256, 512, 0, stream>>>(x, wt, b0, b1, b2, out);
}